// Round 1
// baseline (621.038 us; speedup 1.0000x reference)
//
#include <hip/hip_runtime.h>
#include <math.h>

#define NUM_HEADS   16
#define HEAD_DIM    64
#define KMAXN       64
#define LOCAL_WIN   512
#define LOG_N       17
#define LEAF_START  131072
#define MAX_LEN_TOK 65536
#define ROW         1024      // NUM_HEADS*HEAD_DIM floats per token
#define SLICE       65536     // 64 * ROW floats per partial slice
#define MAXN        34

struct K1Args {
    int nNodes;
    int a[MAXN];      // start token
    int cpb[MAXN];    // chunks per block
    int C[MAXN];      // total chunks
    int CB[MAXN];     // chunk-blocks
    int off[MAXN];    // partial buffer offset (floats)
    int bbase[MAXN];  // first blockIdx for this node
};

struct K2Args {
    int nNodes;
    int K[MAXN];
    int C[MAXN];
    int CB[MAXN];
    int off[MAXN];
    int depth[MAXN];
    int nodeout_off;  // floats
};

__device__ __forceinline__ void f4add(float4& a, const float4& b) {
    a.x += b.x; a.y += b.y; a.z += b.z; a.w += b.w;
}

// ---------------- K1: strided chunk-mean reduction (sums only; 1/C applied in K2)
__global__ __launch_bounds__(256) void k1_reduce(const float* __restrict__ v,
                                                 float* __restrict__ ws,
                                                 K1Args A) {
    int b = blockIdx.x;
    int node = 0;
    for (int i = 1; i < A.nNodes; ++i)
        if (b >= A.bbase[i]) node = i;     // uniform scalar scan
    int lb  = b - A.bbase[node];
    int CB  = A.CB[node];
    int k   = lb / CB;
    int cb  = lb - k * CB;
    int c0  = cb * A.cpb[node];
    int c1  = c0 + A.cpb[node];
    int C   = A.C[node];
    if (c1 > C) c1 = C;

    int j = threadIdx.x;                   // float4 index within the 1024-float row
    const float* vp = v + (long)(A.a[node] + k) * ROW + (long)c0 * SLICE + j * 4;
    const long stride = (long)SLICE;       // 64 tokens * ROW floats

    float4 a0 = make_float4(0.f, 0.f, 0.f, 0.f);
    float4 a1 = a0, a2 = a0, a3 = a0;
    int c = c0;
    for (; c + 4 <= c1; c += 4) {
        float4 x0 = *(const float4*)(vp);
        float4 x1 = *(const float4*)(vp + stride);
        float4 x2 = *(const float4*)(vp + 2 * stride);
        float4 x3 = *(const float4*)(vp + 3 * stride);
        f4add(a0, x0); f4add(a1, x1); f4add(a2, x2); f4add(a3, x3);
        vp += 4 * stride;
    }
    for (; c < c1; ++c) {
        float4 x = *(const float4*)(vp);
        f4add(a0, x);
        vp += stride;
    }
    f4add(a0, a1); f4add(a2, a3); f4add(a0, a2);
    *(float4*)(ws + (long)A.off[node] + (long)cb * SLICE + k * ROW + j * 4) = a0;
}

// ---------------- K2: per-(node, head) attention over f (K <= 64), single wave
__global__ __launch_bounds__(64) void k2_node_attn(const float* __restrict__ ws_in,
                                                   const float* __restrict__ q,
                                                   const float* __restrict__ W,
                                                   const float* __restrict__ temp,
                                                   float* __restrict__ ws_out,
                                                   K2Args A) {
    int h    = blockIdx.x;
    int node = blockIdx.y;
    int lane = threadIdx.x;                // = d
    int K    = A.K[node];
    int CB   = A.CB[node];
    int dep  = A.depth[node];
    const float* pf = ws_in + (long)A.off[node];

    __shared__ float qs[64];
    __shared__ float fs[64 * 64];
    __shared__ float sv[64];
    __shared__ float ps[64];

    qs[lane] = q[h * 64 + lane];
    __syncthreads();

    // q_depth[d] = q[d] + sum_e q[e] * W[dep][d][e]
    float qd = qs[lane];
    const float* Wr = W + ((long)dep * 64 + lane) * 64;
    for (int e = 0; e < 64; ++e) qd += qs[e] * Wr[e];

    float t  = temp[dep];
    float sp = log1pf(expf(t));
    float scale = 1.0f / ((sp + 1e-6f) * 8.0f);
    float invC  = 1.0f / (float)A.C[node];

    for (int k = 0; k < K; ++k) {
        float fv = 0.f;
        for (int cb = 0; cb < CB; ++cb)
            fv += pf[(long)cb * SLICE + k * ROW + h * 64 + lane];
        fv *= invC;
        fs[k * 64 + lane] = fv;
        float p = qd * fv;
        #pragma unroll
        for (int m = 1; m < 64; m <<= 1) p += __shfl_xor(p, m, 64);
        if (lane == 0) sv[k] = p * scale;
    }
    __syncthreads();

    float s  = (lane < K) ? sv[lane] : -1e30f;
    float mx = s;
    #pragma unroll
    for (int m = 1; m < 64; m <<= 1) mx = fmaxf(mx, __shfl_xor(mx, m, 64));
    float e = (lane < K) ? expf(s - mx) : 0.f;
    float S = e;
    #pragma unroll
    for (int m = 1; m < 64; m <<= 1) S += __shfl_xor(S, m, 64);
    ps[lane] = e / S;
    __syncthreads();

    float o = 0.f;
    for (int k = 0; k < K; ++k) o += ps[k] * fs[k * 64 + lane];
    ws_out[(long)A.nodeout_off + node * ROW + h * 64 + lane] = o;
}

// ---------------- K3: local-window attention + combine with tree mean
__global__ __launch_bounds__(256) void k3_local(const float* __restrict__ v,
                                                const float* __restrict__ q,
                                                const float* __restrict__ ws,
                                                int nodeout_off, int nNodes, int pos,
                                                float* __restrict__ out) {
    int h    = blockIdx.x;
    int lane = threadIdx.x & 63;           // = d
    int w    = threadIdx.x >> 6;           // wave 0..3
    int nloc = pos < LOCAL_WIN ? pos : LOCAL_WIN;
    int t0   = pos - nloc;

    __shared__ float sc[LOCAL_WIN];
    __shared__ float red[4][64];
    __shared__ float mS[2];

    float qv = q[h * 64 + lane];
    const float* vb = v + (long)t0 * ROW + h * 64 + lane;

    // scores
    for (int k = w; k < nloc; k += 4) {
        float p = vb[(long)k * ROW] * qv;
        #pragma unroll
        for (int m = 1; m < 64; m <<= 1) p += __shfl_xor(p, m, 64);
        if (lane == 0) sc[k] = p * 0.125f;
    }
    __syncthreads();

    // block max
    float mx = -1e30f;
    for (int k = threadIdx.x; k < nloc; k += 256) mx = fmaxf(mx, sc[k]);
    #pragma unroll
    for (int m = 1; m < 64; m <<= 1) mx = fmaxf(mx, __shfl_xor(mx, m, 64));
    if (lane == 0) red[w][0] = mx;
    __syncthreads();
    if (threadIdx.x == 0) {
        float m2 = red[0][0];
        m2 = fmaxf(m2, red[1][0]); m2 = fmaxf(m2, red[2][0]); m2 = fmaxf(m2, red[3][0]);
        mS[0] = m2;
    }
    __syncthreads();
    float m = mS[0];

    // exp + block sum
    float sum = 0.f;
    for (int k = threadIdx.x; k < nloc; k += 256) {
        float e = expf(sc[k] - m);
        sc[k] = e;
        sum += e;
    }
    #pragma unroll
    for (int mm = 1; mm < 64; mm <<= 1) sum += __shfl_xor(sum, mm, 64);
    if (lane == 0) red[w][1] = sum;
    __syncthreads();
    if (threadIdx.x == 0) mS[1] = red[0][1] + red[1][1] + red[2][1] + red[3][1];
    __syncthreads();
    float S = mS[1];

    // weighted V
    float acc = 0.f;
    for (int k = w; k < nloc; k += 4) acc += sc[k] * vb[(long)k * ROW];
    __syncthreads();           // red[][] reuse
    red[w][lane] = acc;
    __syncthreads();

    if (w == 0) {
        float tot = red[0][lane] + red[1][lane] + red[2][lane] + red[3][lane];
        tot = (nloc > 0) ? tot / S : 0.f;
        float tr = 0.f;
        for (int n = 0; n < nNodes; ++n)
            tr += ws[(long)nodeout_off + n * ROW + h * 64 + lane];
        if (nNodes > 0) tr /= (float)nNodes;
        out[h * 64 + lane] = tot + tr;
    }
}

static int floor_log2_host(unsigned x) { int r = 0; while (x >>= 1) ++r; return r; }

extern "C" void kernel_launch(void* const* d_in, const int* in_sizes, int n_in,
                              void* d_out, int out_size, void* d_ws, size_t ws_size,
                              hipStream_t stream) {
    const float* v    = (const float*)d_in[0];
    const float* q    = (const float*)d_in[1];
    const float* W    = (const float*)d_in[2];
    const float* temp = (const float*)d_in[3];
    float* out        = (float*)d_out;
    float* ws         = (float*)d_ws;

    int pos = in_sizes[0] / ROW;

    // cover set (host, deterministic from in_sizes -> graph-capture safe)
    int n_nodes = 0;
    int nv[MAXN], nd[MAXN];
    if (pos > 0) {
        long l = LEAF_START;
        long r = LEAF_START + (pos < MAX_LEN_TOK ? pos : MAX_LEN_TOK);
        while (l < r) {
            if (l & 1) { nv[n_nodes] = (int)l; nd[n_nodes] = LOG_N - floor_log2_host((unsigned)l); ++n_nodes; ++l; }
            if (r & 1) { --r; nv[n_nodes] = (int)r; nd[n_nodes] = LOG_N - floor_log2_host((unsigned)r); ++n_nodes; }
            l >>= 1; r >>= 1;
        }
    }

    // choose chunks-per-block: smallest in {32,64,128,256,1024} whose partial
    // buffer fits in ws
    int cpb_choice = 1024;
    for (int cand : {32, 64, 128, 256, 1024}) {
        long tot_cb = 0;
        for (int i = 0; i < n_nodes; ++i) {
            int L = 1 << nd[i];
            int C = (L > KMAXN) ? L / KMAXN : 1;
            tot_cb += (C + cand - 1) / cand;
        }
        long need = (tot_cb * (long)SLICE + (long)n_nodes * ROW) * 4;
        if (need <= (long)ws_size) { cpb_choice = cand; break; }
    }

    K1Args A1{}; K2Args A2{};
    A1.nNodes = n_nodes; A2.nNodes = n_nodes;
    int off = 0, bb = 0;
    for (int i = 0; i < n_nodes; ++i) {
        int depth = nd[i];
        int L = 1 << depth;
        int a = (nv[i] << depth) - LEAF_START;
        int K = (L < KMAXN) ? L : KMAXN;
        int C = (L > KMAXN) ? L / KMAXN : 1;
        int CB = (C + cpb_choice - 1) / cpb_choice;
        int cpb = (C + CB - 1) / CB;
        A1.a[i] = a;   A1.cpb[i] = cpb; A1.C[i] = C; A1.CB[i] = CB;
        A1.off[i] = off; A1.bbase[i] = bb;
        A2.K[i] = K;   A2.C[i] = C;    A2.CB[i] = CB;
        A2.off[i] = off; A2.depth[i] = depth;
        off += CB * SLICE;
        bb  += K * CB;
    }
    A2.nodeout_off = off;

    if (bb > 0) {
        hipLaunchKernelGGL(k1_reduce, dim3(bb), dim3(256), 0, stream, v, ws, A1);
        hipLaunchKernelGGL(k2_node_attn, dim3(NUM_HEADS, n_nodes), dim3(64), 0, stream,
                           ws, q, W, temp, ws, A2);
    }
    hipLaunchKernelGGL(k3_local, dim3(NUM_HEADS), dim3(256), 0, stream,
                       v, q, ws, A2.nodeout_off, n_nodes, pos, out);
}

// Round 2
// 324.038 us; speedup vs baseline: 1.9166x; 1.9166x over previous
//
#include <hip/hip_runtime.h>
#include <math.h>

#define NUM_HEADS   16
#define HEAD_DIM    64
#define KMAXN       64
#define LOCAL_WIN   512
#define LOG_N       17
#define LEAF_START  131072
#define MAX_LEN_TOK 65536
#define ROW         1024      // NUM_HEADS*HEAD_DIM floats per token
#define SLICE       65536     // 64 tokens * ROW floats per partial slice
#define MAXN        34

struct K1Args {
    int nNodes;
    int a[MAXN];      // start token
    int cpb[MAXN];    // chunks per block
    int C[MAXN];      // total chunks
    int CB[MAXN];     // chunk-blocks
    int off[MAXN];    // partial buffer offset (floats)
    int bbase[MAXN];  // first blockIdx for this node
};

struct K2Args {
    int nNodes;
    int K[MAXN];
    int C[MAXN];
    int CB[MAXN];
    int off[MAXN];    // partial offsets (input to k1b)
    int depth[MAXN];
};

__device__ __forceinline__ void f4add(float4& a, const float4& b) {
    a.x += b.x; a.y += b.y; a.z += b.z; a.w += b.w;
}

// ---------------- K1: strided chunk-sum partials (1/C applied in k1b)
__global__ __launch_bounds__(256) void k1_reduce(const float* __restrict__ v,
                                                 float* __restrict__ ws,
                                                 K1Args A) {
    int b = blockIdx.x;
    int node = 0;
    for (int i = 1; i < A.nNodes; ++i)
        if (b >= A.bbase[i]) node = i;     // uniform scalar scan
    int lb  = b - A.bbase[node];
    int CB  = A.CB[node];
    int k   = lb / CB;
    int cb  = lb - k * CB;
    int c0  = cb * A.cpb[node];
    int c1  = c0 + A.cpb[node];
    int C   = A.C[node];
    if (c1 > C) c1 = C;

    int j = threadIdx.x;
    const float* vp = v + (long)(A.a[node] + k) * ROW + (long)c0 * SLICE + j * 4;
    const long st = (long)SLICE;           // 64 tokens

    float4 a0 = make_float4(0.f,0.f,0.f,0.f);
    float4 a1=a0,a2=a0,a3=a0,a4=a0,a5=a0,a6=a0,a7=a0;
    int c = c0;
    for (; c + 8 <= c1; c += 8) {
        float4 x0 = *(const float4*)(vp);
        float4 x1 = *(const float4*)(vp + st);
        float4 x2 = *(const float4*)(vp + 2*st);
        float4 x3 = *(const float4*)(vp + 3*st);
        float4 x4 = *(const float4*)(vp + 4*st);
        float4 x5 = *(const float4*)(vp + 5*st);
        float4 x6 = *(const float4*)(vp + 6*st);
        float4 x7 = *(const float4*)(vp + 7*st);
        f4add(a0,x0); f4add(a1,x1); f4add(a2,x2); f4add(a3,x3);
        f4add(a4,x4); f4add(a5,x5); f4add(a6,x6); f4add(a7,x7);
        vp += 8*st;
    }
    for (; c < c1; ++c) { f4add(a0, *(const float4*)(vp)); vp += st; }
    f4add(a0,a1); f4add(a2,a3); f4add(a4,a5); f4add(a6,a7);
    f4add(a0,a2); f4add(a4,a6); f4add(a0,a4);
    *(float4*)(ws + (long)A.off[node] + (long)cb * SLICE + k * ROW + j * 4) = a0;
}

// ---------------- K1b: reduce CB partial slices -> final f (with 1/C)
__global__ __launch_bounds__(256) void k1b_finalize(const float* __restrict__ ws_in,
                                                    float* __restrict__ f,
                                                    K2Args A) {
    int node = blockIdx.y;
    int k    = blockIdx.x;
    if (k >= A.K[node]) return;
    int CB = A.CB[node];
    const float* pf = ws_in + (long)A.off[node] + (long)k * ROW + threadIdx.x * 4;
    float4 acc = make_float4(0.f,0.f,0.f,0.f);
    for (int cb = 0; cb < CB; ++cb)
        f4add(acc, *(const float4*)(pf + (long)cb * SLICE));
    float invC = 1.0f / (float)A.C[node];
    acc.x*=invC; acc.y*=invC; acc.z*=invC; acc.w*=invC;
    *(float4*)(f + ((long)node * 64 + k) * ROW + threadIdx.x * 4) = acc;
}

// ---------------- K2: per-(node,head) attention over f (K <= 64), 4 waves
__global__ __launch_bounds__(256) void k2_node_attn(const float* __restrict__ f,
                                                    const float* __restrict__ q,
                                                    const float* __restrict__ W,
                                                    const float* __restrict__ temp,
                                                    float* __restrict__ node_out,
                                                    K2Args A) {
    int h    = blockIdx.x;
    int node = blockIdx.y;
    int lane = threadIdx.x & 63;           // = d
    int w    = threadIdx.x >> 6;           // wave 0..3
    int K    = A.K[node];
    int dep  = A.depth[node];
    const float* pf = f + (long)node * SLICE + h * 64;   // row k at pf + k*ROW

    __shared__ float qs[64], qds[64], sv[64], ps[64];
    __shared__ float red[4][64];

    if (threadIdx.x < 64) qs[lane] = q[h * 64 + lane];
    __syncthreads();

    float qp = 0.f;
    const float* Wr = W + ((long)dep * 64 + lane) * 64;
    #pragma unroll
    for (int e = w * 16; e < w * 16 + 16; ++e) qp += qs[e] * Wr[e];
    red[w][lane] = qp;
    __syncthreads();
    if (w == 0) qds[lane] = qs[lane] + red[0][lane] + red[1][lane] + red[2][lane] + red[3][lane];
    __syncthreads();
    float qd = qds[lane];

    float sp    = log1pf(expf(temp[dep]));
    float scale = 1.0f / ((sp + 1e-6f) * 8.0f);

    for (int k = w; k < K; k += 4) {
        float p = qd * pf[(long)k * ROW + lane];
        #pragma unroll
        for (int m = 1; m < 64; m <<= 1) p += __shfl_xor(p, m, 64);
        if (lane == 0) sv[k] = p * scale;
    }
    __syncthreads();

    if (w == 0) {
        float s  = (lane < K) ? sv[lane] : -1e30f;
        float mx = s;
        #pragma unroll
        for (int m = 1; m < 64; m <<= 1) mx = fmaxf(mx, __shfl_xor(mx, m, 64));
        float e = (lane < K) ? expf(s - mx) : 0.f;
        float S = e;
        #pragma unroll
        for (int m = 1; m < 64; m <<= 1) S += __shfl_xor(S, m, 64);
        ps[lane] = e / S;
    }
    __syncthreads();

    float o = 0.f;
    for (int k = w; k < K; k += 4) o += ps[k] * pf[(long)k * ROW + lane];
    red[w][lane] = o;
    __syncthreads();
    if (w == 0)
        node_out[node * ROW + h * 64 + lane] =
            red[0][lane] + red[1][lane] + red[2][lane] + red[3][lane];
}

// ---------------- K3: local-window attention + combine (512 thr = 8 waves/head)
__global__ __launch_bounds__(512) void k3_local(const float* __restrict__ v,
                                                const float* __restrict__ q,
                                                const float* __restrict__ node_out,
                                                int nNodes, int pos,
                                                float* __restrict__ out) {
    int h    = blockIdx.x;
    int tid  = threadIdx.x;
    int lane = tid & 63;
    int w    = tid >> 6;                   // wave 0..7
    int nloc = pos < LOCAL_WIN ? pos : LOCAL_WIN;
    int t0   = pos - nloc;

    __shared__ float qs[64];
    __shared__ float sc[LOCAL_WIN];
    __shared__ float red[8][64];
    __shared__ float wred[16];
    __shared__ float mS[2];

    if (tid < 64) qs[tid] = q[h * 64 + tid];
    __syncthreads();

    // phase A: one token per thread; serial dot over d
    float s = -1e30f;
    if (tid < nloc) {
        const float* vr = v + (long)(t0 + tid) * ROW + h * 64;
        float acc = 0.f;
        #pragma unroll 8
        for (int d = 0; d < 64; ++d) acc += qs[d] * vr[d];
        s = acc * 0.125f;
    }
    float mx = s;
    #pragma unroll
    for (int m = 1; m < 64; m <<= 1) mx = fmaxf(mx, __shfl_xor(mx, m, 64));
    if (lane == 0) wred[w] = mx;
    __syncthreads();
    if (tid == 0) {
        float m2 = wred[0];
        for (int i = 1; i < 8; ++i) m2 = fmaxf(m2, wred[i]);
        mS[0] = m2;
    }
    __syncthreads();
    float m = mS[0];

    float e = (tid < nloc) ? expf(s - m) : 0.f;
    sc[tid] = e;
    float su = e;
    #pragma unroll
    for (int mm = 1; mm < 64; mm <<= 1) su += __shfl_xor(su, mm, 64);
    if (lane == 0) wred[8 + w] = su;
    __syncthreads();
    if (tid == 0) {
        float S2 = 0.f;
        for (int i = 0; i < 8; ++i) S2 += wred[8 + i];
        mS[1] = S2;
    }
    __syncthreads();
    float S = mS[1];

    // phase B: lane = d, wave w handles tokens [w*64, w*64+64)
    float acc = 0.f;
    {
        const float* vb = v + (long)t0 * ROW + h * 64 + lane;
        int tb = w * 64;
        #pragma unroll 4
        for (int i = 0; i < 64; ++i) {
            int t = tb + i;
            if (t < nloc) acc += sc[t] * vb[(long)t * ROW];
        }
    }
    red[w][lane] = acc;
    __syncthreads();

    if (w == 0) {
        float tot = 0.f;
        #pragma unroll
        for (int i = 0; i < 8; ++i) tot += red[i][lane];
        tot = (nloc > 0) ? tot / S : 0.f;
        float tr = 0.f;
        for (int n = 0; n < nNodes; ++n) tr += node_out[n * ROW + h * 64 + lane];
        if (nNodes > 0) tr /= (float)nNodes;
        out[h * 64 + lane] = tot + tr;
    }
}

static int floor_log2_host(unsigned x) { int r = 0; while (x >>= 1) ++r; return r; }

extern "C" void kernel_launch(void* const* d_in, const int* in_sizes, int n_in,
                              void* d_out, int out_size, void* d_ws, size_t ws_size,
                              hipStream_t stream) {
    const float* v    = (const float*)d_in[0];
    const float* q    = (const float*)d_in[1];
    const float* W    = (const float*)d_in[2];
    const float* temp = (const float*)d_in[3];
    float* out        = (float*)d_out;
    float* ws         = (float*)d_ws;

    int pos = in_sizes[0] / ROW;

    int n_nodes = 0;
    int nv[MAXN], nd[MAXN];
    if (pos > 0) {
        long l = LEAF_START;
        long r = LEAF_START + (pos < MAX_LEN_TOK ? pos : MAX_LEN_TOK);
        while (l < r) {
            if (l & 1) { nv[n_nodes] = (int)l; nd[n_nodes] = LOG_N - floor_log2_host((unsigned)l); ++n_nodes; ++l; }
            if (r & 1) { --r; nv[n_nodes] = (int)r; nd[n_nodes] = LOG_N - floor_log2_host((unsigned)r); ++n_nodes; }
            l >>= 1; r >>= 1;
        }
    }

    // pick chunks-per-block: smallest that fits ws
    // ws layout: partials [tot_cb*SLICE] | f [n_nodes*SLICE] | node_out [n_nodes*ROW]
    int cpb_choice = 1024;
    for (int cand : {16, 32, 64, 128, 256, 512, 1024}) {
        long tot_cb = 0;
        for (int i = 0; i < n_nodes; ++i) {
            int L = 1 << nd[i];
            int C = (L > KMAXN) ? L / KMAXN : 1;
            tot_cb += (C + cand - 1) / cand;
        }
        long need = ((tot_cb + n_nodes) * (long)SLICE + (long)n_nodes * ROW) * 4;
        if (need <= (long)ws_size) { cpb_choice = cand; break; }
    }

    K1Args A1{}; K2Args A2{};
    A1.nNodes = n_nodes; A2.nNodes = n_nodes;
    int off = 0, bb = 0;
    for (int i = 0; i < n_nodes; ++i) {
        int depth = nd[i];
        int L = 1 << depth;
        int a = (nv[i] << depth) - LEAF_START;
        int K = (L < KMAXN) ? L : KMAXN;
        int C = (L > KMAXN) ? L / KMAXN : 1;
        int CB = (C + cpb_choice - 1) / cpb_choice;
        int cpb = (C + CB - 1) / CB;
        A1.a[i] = a;   A1.cpb[i] = cpb; A1.C[i] = C; A1.CB[i] = CB;
        A1.off[i] = off; A1.bbase[i] = bb;
        A2.K[i] = K;   A2.C[i] = C;    A2.CB[i] = CB;
        A2.off[i] = off; A2.depth[i] = depth;
        off += CB * SLICE;
        bb  += K * CB;
    }
    float* f_buf     = ws + (long)off;                     // n_nodes * SLICE
    float* node_outp = f_buf + (long)n_nodes * SLICE;      // n_nodes * ROW

    if (n_nodes > 0) {
        hipLaunchKernelGGL(k1_reduce, dim3(bb), dim3(256), 0, stream, v, ws, A1);
        hipLaunchKernelGGL(k1b_finalize, dim3(64, n_nodes), dim3(256), 0, stream,
                           ws, f_buf, A2);
        hipLaunchKernelGGL(k2_node_attn, dim3(NUM_HEADS, n_nodes), dim3(256), 0, stream,
                           f_buf, q, W, temp, node_outp, A2);
    }
    hipLaunchKernelGGL(k3_local, dim3(NUM_HEADS), dim3(512), 0, stream,
                       v, q, node_outp, n_nodes, pos, out);
}